// Round 1
// baseline (53.436 us; speedup 1.0000x reference)
//
#include <hip/hip_runtime.h>

// Problem constants (from setup_inputs): B=256, lens_x=32, H_SP=16, W_SP=10, C=768
#define LENS_X 32
#define NB     256
#define HSP    16
#define WSP    10
#define W2N    (WSP/2)          // 5
#define CC     768
#define C4     (CC/4)           // 192 float4s per token
#define TOK    (LENS_X + HSP*WSP)  // 192 tokens

// Work decomposition:
//   Region 1: N1 = B*LENS_X*C4 float4 copies (prefix tokens)
//   Region 2: N2 = B*HSP*W2N*C4 items; each handles a 2-token x 4-channel block
#define N1 (NB * LENS_X * C4)        // 1,572,864
#define N2 (NB * HSP * W2N * C4)     // 3,932,160
#define NTOT (N1 + N2)               // 5,505,024

__global__ __launch_bounds__(256) void sgn_kernel(const float* __restrict__ x,
                                                  const float* __restrict__ cw,
                                                  float* __restrict__ out) {
    int i = blockIdx.x * blockDim.x + threadIdx.x;
    if (i < N1) {
        // copy region: i -> (b, t, c4), all contiguous in memory => straight copy
        // layout of the first N1 float4s of x is exactly tokens [0,32) of each batch?
        // No: tokens 0..31 of batch b are at b*TOK*CC, not contiguous across b.
        int c4 = i % C4;
        int t  = (i / C4) % LENS_X;
        int b  = i / (C4 * LENS_X);
        int off = (b * TOK + t) * CC + c4 * 4;
        float4 v = *(const float4*)(x + off);
        *(float4*)(out + off) = v;
    } else if (i < NTOT) {
        int j  = i - N1;
        int c4 = j % C4;
        int w2 = (j / C4) % W2N;
        int h  = (j / (C4 * W2N)) % HSP;
        int b  = j / (C4 * W2N * HSP);

        int row0 = (b * TOK + LENS_X + h * WSP + 2 * w2) * CC + c4 * 4;
        float4 t0 = *(const float4*)(x + row0);        // token 2*w2, channels 4c4..4c4+3
        float4 t1 = *(const float4*)(x + row0 + CC);   // token 2*w2+1

        // complex_weight shape (16,5,384,2): [h][w2][c2][0] at (h*5+w2)*768 + 2*c2
        // float4 at base + 4*c4 gives weights for c2 = 2*c4 (.x) and 2*c4+1 (.z)
        float4 wv = *(const float4*)(cw + (h * W2N + w2) * CC + c4 * 4);

        // quad 0: channels (4c4, 4c4+1); quad 1: channels (4c4+2, 4c4+3)
        float ll0 = (t0.x + t0.y + t1.x + t1.y) * 0.5f;
        float ll1 = (t0.z + t0.w + t1.z + t1.w) * 0.5f;
        float d0  = (wv.x - 1.0f) * ll0 * 0.5f;
        float d1  = (wv.z - 1.0f) * ll1 * 0.5f;

        float4 o0 = make_float4(t0.x + d0, t0.y + d0, t0.z + d1, t0.w + d1);
        float4 o1 = make_float4(t1.x + d0, t1.y + d0, t1.z + d1, t1.w + d1);
        *(float4*)(out + row0)      = o0;
        *(float4*)(out + row0 + CC) = o1;
    }
}

extern "C" void kernel_launch(void* const* d_in, const int* in_sizes, int n_in,
                              void* d_out, int out_size, void* d_ws, size_t ws_size,
                              hipStream_t stream) {
    const float* x  = (const float*)d_in[0];
    const float* cw = (const float*)d_in[1];
    float* out      = (float*)d_out;
    (void)in_sizes; (void)n_in; (void)d_ws; (void)ws_size; (void)out_size;

    int grid = (NTOT + 255) / 256;
    sgn_kernel<<<grid, 256, 0, stream>>>(x, cw, out);
}

// Round 3
// 52.466 us; speedup vs baseline: 1.0185x; 1.0185x over previous
//
#include <hip/hip_runtime.h>

// Problem constants (from setup_inputs): B=256, lens_x=32, H_SP=16, W_SP=10, C=768
#define LENS_X 32
#define NB     256
#define HSP    16
#define WSP    10
#define W2N    (WSP/2)          // 5
#define CC     768
#define C4     (CC/4)           // 192 float4s per token
#define TOK    (LENS_X + HSP*WSP)  // 192 tokens

// Region 1: N1 = B*LENS_X*C4 float4 copies (prefix tokens)
// Region 2: N2 = B*HSP*W2N*C4 items; each handles a 2-token x 4-channel block
#define N1 (NB * LENS_X * C4)        // 1,572,864
#define N2 (NB * HSP * W2N * C4)     // 3,932,160
#define NTOT (N1 + N2)               // 5,505,024

typedef float f4 __attribute__((ext_vector_type(4)));  // clang vector: OK for nontemporal builtins

__global__ __launch_bounds__(256) void sgn_kernel(const float* __restrict__ x,
                                                  const float* __restrict__ cw,
                                                  float* __restrict__ out) {
    int i = blockIdx.x * blockDim.x + threadIdx.x;
    if (i < N1) {
        // prefix copy region: (b, t, c4) — coalesced streaming copy
        int c4 = i % C4;
        int t  = (i / C4) % LENS_X;
        int b  = i / (C4 * LENS_X);
        int off = (b * TOK + t) * CC + c4 * 4;
        f4 v = __builtin_nontemporal_load((const f4*)(x + off));
        __builtin_nontemporal_store(v, (f4*)(out + off));
    } else if (i < NTOT) {
        int j  = i - N1;
        int c4 = j % C4;
        int hw = j / C4;              // b*80 + h*5 + w2, range [0, 256*80)
        int w2 = hw % W2N;
        int h  = (hw / W2N) % HSP;
        int b  = hw / (W2N * HSP);

        int row0 = (b * TOK + LENS_X + h * WSP + 2 * w2) * CC + c4 * 4;
        f4 t0 = __builtin_nontemporal_load((const f4*)(x + row0));      // token 2*w2
        f4 t1 = __builtin_nontemporal_load((const f4*)(x + row0 + CC)); // token 2*w2+1

        // complex_weight shape (16,5,384,2): [h][w2][c2][0] at (h*5+w2)*768 + 2*c2
        // float4 at base + 4*c4 covers c2 = 2*c4 (elem 0) and 2*c4+1 (elem 2).
        // 240KB total -> L2-resident; keep as cached load.
        f4 wv = *(const f4*)(cw + (h * W2N + w2) * CC + c4 * 4);

        // 2-level Haar is orthonormal; only LL is scaled, so
        // out_ij = x_ij + (w-1) * ll / 2 with ll = sum(quad)/2.
        float ll0 = (t0.x + t0.y + t1.x + t1.y) * 0.5f;
        float ll1 = (t0.z + t0.w + t1.z + t1.w) * 0.5f;
        float d0  = (wv.x - 1.0f) * ll0 * 0.5f;
        float d1  = (wv.z - 1.0f) * ll1 * 0.5f;

        f4 o0 = {t0.x + d0, t0.y + d0, t0.z + d1, t0.w + d1};
        f4 o1 = {t1.x + d0, t1.y + d0, t1.z + d1, t1.w + d1};
        __builtin_nontemporal_store(o0, (f4*)(out + row0));
        __builtin_nontemporal_store(o1, (f4*)(out + row0 + CC));
    }
}

extern "C" void kernel_launch(void* const* d_in, const int* in_sizes, int n_in,
                              void* d_out, int out_size, void* d_ws, size_t ws_size,
                              hipStream_t stream) {
    const float* x  = (const float*)d_in[0];
    const float* cw = (const float*)d_in[1];
    float* out      = (float*)d_out;
    (void)in_sizes; (void)n_in; (void)d_ws; (void)ws_size; (void)out_size;

    int grid = (NTOT + 255) / 256;
    sgn_kernel<<<grid, 256, 0, stream>>>(x, cw, out);
}